// Round 14
// baseline (43.540 us; speedup 1.0000x reference)
//
#include <hip/hip_runtime.h>
#include <math.h>

// zc layout: [(j2*16 + kko)][3072 rows][32 w] bf16, chunk-swizzled: logical 8-elem
//   chunk g of row r stored at chunk (g ^ ((r>>1)&3)). Plane = 98304 elems.
// dw layout: [kko(16)][512 k][32 w] bf16, same swizzle keyed on k.
#define ZSLAB 98304
#define DSLAB 16384
#define SBUF  26624    // stage buffer elems: A 18432 + B 8192 (53248 B), BK=64
#define OB_PITCH 776   // Obuf [row48][k*6+j2], k 0..127 (both tiles) + 8 pad

typedef __attribute__((ext_vector_type(8))) __bf16 bf16x8;
typedef __attribute__((ext_vector_type(4))) float  f32x4;

__device__ __forceinline__ unsigned short f2bf(float f) {
  union { float f; unsigned u; } v; v.f = f;
  unsigned r = v.u + 0x7fffu + ((v.u >> 16) & 1u);   // RNE
  return (unsigned short)(r >> 16);
}
__device__ __forceinline__ float bf2f_lo(unsigned u) {
  union { unsigned u; float f; } v; v.u = u << 16; return v.f;
}
__device__ __forceinline__ float bf2f_hi(unsigned u) {
  union { unsigned u; float f; } v; v.u = u & 0xffff0000u; return v.f;
}

__device__ const float DBC[8][8] = {
  { 0.35355339f,  0.35355339f,  0.35355339f,  0.35355339f,  0.35355339f,  0.35355339f,  0.35355339f,  0.35355339f},
  { 0.49039264f,  0.41573481f,  0.27778512f,  0.09754516f, -0.09754516f, -0.27778512f, -0.41573481f, -0.49039264f},
  { 0.46193977f,  0.19134172f, -0.19134172f, -0.46193977f, -0.46193977f, -0.19134172f,  0.19134172f,  0.46193977f},
  { 0.41573481f, -0.09754516f, -0.49039264f, -0.27778512f,  0.27778512f,  0.49039264f,  0.09754516f, -0.41573481f},
  { 0.35355339f, -0.35355339f, -0.35355339f,  0.35355339f,  0.35355339f, -0.35355339f, -0.35355339f,  0.35355339f},
  { 0.27778512f, -0.49039264f,  0.09754516f,  0.41573481f, -0.41573481f, -0.09754516f,  0.49039264f, -0.27778512f},
  { 0.19134172f, -0.46193977f,  0.46193977f, -0.19134172f, -0.19134172f,  0.46193977f, -0.46193977f,  0.19134172f},
  { 0.09754516f, -0.27778512f,  0.41573481f, -0.49039264f,  0.49039264f, -0.41573481f,  0.27778512f, -0.09754516f}
};

// ---------------- 1) pack + dw build fused. grid (512, 2) x 256 threads. (unchanged)
__global__ __launch_bounds__(256) void pack_all(const float* __restrict__ x,
                                                unsigned short* __restrict__ zc,
                                                unsigned short* __restrict__ dwf) {
  const int h = blockIdx.x, t = threadIdx.x;

  {
    const int idx = (blockIdx.y * 512 + blockIdx.x) * 256 + t;
    const int k = idx >> 9, w = idx & 511;
    const int n = (k * (2 * w + 1)) & 2047;                     // exact angle reduction
    const float c = __cosf((float)n * 0.0030679615757712823f);  // pi/1024
    const float scale = (k == 0) ? 0.04419417382415922f : 0.0625f;
    const int kko = w >> 5, g = (w >> 3) & 3, e = w & 7, s = (k >> 1) & 3;
    dwf[(size_t)kko * DSLAB + k * 32 + ((g ^ s) << 3) + e] = f2bf(c * scale);
  }

  const int c0 = blockIdx.y * 2048 + t * 8;   // this thread's 8 cols = one w, all j
  const float* xb = x + (size_t)(h * 8) * 4096 + c0;
  float q[8][8];
#pragma unroll
  for (int i = 0; i < 8; ++i) {
    float4 a = *reinterpret_cast<const float4*>(xb + (size_t)i * 4096);
    float4 b = *reinterpret_cast<const float4*>(xb + (size_t)i * 4096 + 4);
    q[i][0] = floorf(a.x * 255.0f); q[i][1] = floorf(a.y * 255.0f);
    q[i][2] = floorf(a.z * 255.0f); q[i][3] = floorf(a.w * 255.0f);
    q[i][4] = floorf(b.x * 255.0f); q[i][5] = floorf(b.y * 255.0f);
    q[i][6] = floorf(b.z * 255.0f); q[i][7] = floorf(b.w * 255.0f);
  }
  const int w0 = c0 >> 3;
  const int kko = w0 >> 5, g = (w0 >> 3) & 3, e = w0 & 7;
#pragma unroll
  for (int m = 2; m < 8; ++m) {
    const int row = h * 6 + (m - 2);
    const int s = (row >> 1) & 3;
    const size_t base = (size_t)row * 32 + ((g ^ s) << 3) + e;
#pragma unroll
    for (int j = 2; j < 8; ++j) {
      float v = 0.0f;
#pragma unroll
      for (int i = 0; i < 8; ++i) v = fmaf(DBC[m][i], q[i][j], v);
      zc[(size_t)((j - 2) * 16 + kko) * ZSLAB + base] = f2bf(v);
    }
  }
}

// ---------------- 2) fused paired-tile GEMM + interleave. grid 256, 768 thr, BK=64.
// Block (mt 0..63, np 0..3): out rows [mt*64,+64), cols [np*1024,+1024).
// 12 waves (j2, nh); per stage (BK=64 = 2 k-steps): 24 MFMA/wave, 14 b128 reads.
// Stage buf: A [6 j2][2 s2][48 r][32 w] + B [2 s2][128 k][32 w]; 2-deep (106496 B).
// Loads: waves 0-8: 4/stage (A); waves 9-10: 8/stage (B); wave 11: 0 (zero-rows).
__device__ __forceinline__ void gload16(const unsigned short* g, unsigned short* l) {
  __builtin_amdgcn_global_load_lds(
      (__attribute__((address_space(1))) void*)(g),
      (__attribute__((address_space(3))) void*)(l),
      16, 0, 0);
}

__global__ __launch_bounds__(768, 3) void fused_dct(const unsigned short* __restrict__ zc,
                                                    const unsigned short* __restrict__ dwf,
                                                    float* __restrict__ out) {
  const int bid = blockIdx.x;     // bid = np*64+mt -> XCD = mt%8: same-mt blocks share L2
  const int mt  = bid & 63;
  const int np  = bid >> 6;

  // LDS: 2 stage buffers x 53248 B = 106496 B. Obuf (48*776*2 = 74496 B) aliases after.
  __shared__ __align__(16) unsigned char SM[106496];
  unsigned short* SMu  = (unsigned short*)SM;
  unsigned short* Obuf = (unsigned short*)SM;

  const int tid  = threadIdx.x;
  const int lane = tid & 63;
  const int wv   = tid >> 6;        // 0..11
  const int j2   = wv >> 1;         // 0..5 = j-2
  const int nh   = wv & 1;          // N-half within a tile (32 k)
  const int l15  = lane & 15;
  const int hi   = lane >> 4;

  // staging (m104: each issue = wave-uniform LDS base + lane*16B):
  // A chunk f = q*576 + tid (q=0..3), f -> [j2f = f/384][s2 = (f%384)/192][rem = f%192]
  // B chunk g = q*128 + (tid-576) (q=0..7), g -> [s2 = g>>9][c = g&511]
  const unsigned short *sA[4], *sB[8];
  int dA[4], dB[8];
  if (tid < 576) {
#pragma unroll
    for (int q = 0; q < 4; ++q) {
      const int f = q * 576 + tid;
      sA[q] = zc + (size_t)((f / 384) * 16 + (f % 384) / 192) * ZSLAB + mt * 1536 +
              (f % 192) * 8;
      dA[q] = f * 8;
    }
  } else if (tid < 704) {
#pragma unroll
    for (int q = 0; q < 8; ++q) {
      const int g = q * 128 + (tid - 576);
      sB[q] = dwf + (size_t)(g >> 9) * DSLAB + np * 4096 + (g & 511) * 8;
      dB[q] = 18432 + g * 8;
    }
  }

  // STAGE(buf, kk): stage kk covers zc/dw slabs {2kk, 2kk+1}.
#define STAGE(buf, kk)                                                        \
  do {                                                                        \
    unsigned short* L_ = SMu + (buf) * SBUF;                                  \
    if (tid < 576) {                                                          \
      _Pragma("unroll")                                                       \
      for (int q_ = 0; q_ < 4; ++q_)                                          \
        gload16(sA[q_] + (size_t)(2 * (kk)) * ZSLAB, L_ + dA[q_]);            \
    } else if (tid < 704) {                                                   \
      _Pragma("unroll")                                                       \
      for (int q_ = 0; q_ < 8; ++q_)                                          \
        gload16(sB[q_] + (size_t)(2 * (kk)) * DSLAB, L_ + dB[q_]);            \
    }                                                                         \
  } while (0)

  // wave-classed counted waits; wave 11 streams zero rows instead.
  float* const zbase = out + (size_t)(mt * 64) * 4096 + np * 1024;
#define WAITW(na, nb, t)                                                      \
  do {                                                                        \
    if (wv < 9) {                                                             \
      asm volatile("s_waitcnt vmcnt(" #na ")" ::: "memory");                  \
      __builtin_amdgcn_sched_barrier(0);                                      \
    } else if (wv < 11) {                                                     \
      asm volatile("s_waitcnt vmcnt(" #nb ")" ::: "memory");                  \
      __builtin_amdgcn_sched_barrier(0);                                      \
    } else {                                                                  \
      _Pragma("unroll")                                                       \
      for (int q_ = 0; q_ < 8; ++q_) {                                        \
        const int e_ = (t) * 8 + q_;          /* 0..63 */                     \
        const int r16_ = e_ >> 2;             /* zero row 0..15 */            \
        float* p_ = zbase + (size_t)((r16_ >> 1) * 8 + (r16_ & 1)) * 4096 +   \
                    (e_ & 3) * 256 + lane * 4;                                \
        *reinterpret_cast<f32x4*>(p_) = (f32x4){0.f, 0.f, 0.f, 0.f};          \
      }                                                                       \
    }                                                                         \
  } while (0)

  // read offsets (producer swizzle: chunk ^= (row>>1)&3; bases mult. of 16)
  int aoff[2][3], boff[2][2][2];   // [ks][mf], [ks][tt][nf]
#pragma unroll
  for (int ks = 0; ks < 2; ++ks) {
#pragma unroll
    for (int mf = 0; mf < 3; ++mf) {
      const int r_ = mf * 16 + l15;
      aoff[ks][mf] = (j2 * 2 + ks) * 1536 + r_ * 32 + ((hi ^ ((r_ >> 1) & 3)) << 3);
    }
#pragma unroll
    for (int tt = 0; tt < 2; ++tt)
#pragma unroll
      for (int nf = 0; nf < 2; ++nf) {
        const int k_ = tt * 64 + nh * 32 + nf * 16 + l15;
        boff[ks][tt][nf] = 18432 + ks * 4096 + k_ * 32 + ((hi ^ ((k_ >> 1) & 3)) << 3);
      }
  }

  f32x4 accA[3][2] = {}, accB[3][2] = {};

  STAGE(0, 0); STAGE(1, 1);
#pragma unroll
  for (int t = 0; t < 8; ++t) {
    if (t <= 6) WAITW(4, 8, t); else WAITW(0, 0, t);
    __builtin_amdgcn_s_barrier();          // stage t visible to all waves
    {
      const unsigned short* Bb = SMu + (t & 1) * SBUF;
#pragma unroll
      for (int ks = 0; ks < 2; ++ks) {     // two barrier-free k-steps
        bf16x8 afr[3], bfa[2], bfb[2];
#pragma unroll
        for (int mf = 0; mf < 3; ++mf)
          afr[mf] = *reinterpret_cast<const bf16x8*>(Bb + aoff[ks][mf]);
#pragma unroll
        for (int nf = 0; nf < 2; ++nf) {
          bfa[nf] = *reinterpret_cast<const bf16x8*>(Bb + boff[ks][0][nf]);
          bfb[nf] = *reinterpret_cast<const bf16x8*>(Bb + boff[ks][1][nf]);
        }
        __builtin_amdgcn_s_setprio(1);     // T5: pure-MFMA cluster (12 MFMA)
#pragma unroll
        for (int mf = 0; mf < 3; ++mf) {
          accA[mf][0] = __builtin_amdgcn_mfma_f32_16x16x32_bf16(afr[mf], bfa[0], accA[mf][0], 0, 0, 0);
          accA[mf][1] = __builtin_amdgcn_mfma_f32_16x16x32_bf16(afr[mf], bfa[1], accA[mf][1], 0, 0, 0);
          accB[mf][0] = __builtin_amdgcn_mfma_f32_16x16x32_bf16(afr[mf], bfb[0], accB[mf][0], 0, 0, 0);
          accB[mf][1] = __builtin_amdgcn_mfma_f32_16x16x32_bf16(afr[mf], bfb[1], accB[mf][1], 0, 0, 0);
        }
        __builtin_amdgcn_s_setprio(0);
      }
    }
    asm volatile("s_waitcnt lgkmcnt(0)" ::: "memory");  // own reads of buf t&1 done
    __builtin_amdgcn_s_barrier();                       // everyone's reads done
    if (t <= 5) STAGE(t & 1, t + 2);                    // refill with stage t+2
  }
#undef STAGE
#undef WAITW

  // ---- single-pass epilogue: acc -> Obuf[row48][k*6+j2] -> coalesced stores
#pragma unroll
  for (int tt = 0; tt < 2; ++tt)
#pragma unroll
    for (int mf = 0; mf < 3; ++mf)
#pragma unroll
      for (int nf = 0; nf < 2; ++nf)
#pragma unroll
        for (int p = 0; p < 4; ++p) {
          const float vv = tt ? accB[mf][nf][p] : accA[mf][nf][p];
          Obuf[(mf * 16 + hi * 4 + p) * OB_PITCH +
               (tt * 64 + nh * 32 + nf * 16 + l15) * 6 + j2] = f2bf(vv);
        }
  asm volatile("s_waitcnt lgkmcnt(0)" ::: "memory");
  __builtin_amdgcn_s_barrier();            // Obuf fully written

  float* outt = out + (size_t)(mt * 64) * 4096 + np * 1024;
  for (int v = tid; v < 12288; v += 768) { // 48 kept rows x 256 f32x4
    const int row48 = v >> 8;
    const int c4 = (v & 255) << 2;
    const int hg = row48 / 6, mm = row48 - hg * 6;
    const int row64 = hg * 8 + 2 + mm;
    const int kk = c4 >> 3, jb = c4 & 4;
    const unsigned short* Ob = Obuf + row48 * OB_PITCH + kk * 6;
    const unsigned ua = *(const unsigned*)(Ob + (jb >> 1));
    const unsigned ub = *(const unsigned*)(Ob + 4);
    f32x4 val;
    if (jb) {
      val[0] = bf2f_lo(ua); val[1] = bf2f_hi(ua);
      val[2] = bf2f_lo(ub); val[3] = bf2f_hi(ub);
    } else {
      val[0] = 0.f; val[1] = 0.f;
      val[2] = bf2f_lo(ua); val[3] = bf2f_hi(ua);
    }
    *reinterpret_cast<f32x4*>(outt + (size_t)row64 * 4096 + c4) = val;
  }
}

extern "C" void kernel_launch(void* const* d_in, const int* in_sizes, int n_in,
                              void* d_out, int out_size, void* d_ws, size_t ws_size,
                              hipStream_t stream) {
  const float* x = (const float*)d_in[0];
  float* out = (float*)d_out;
  char* ws = (char*)d_ws;

  unsigned short* dwf = (unsigned short*)ws;             // 512 KB
  unsigned short* zc  = (unsigned short*)(ws + 524288);  // 18.87 MB

  pack_all<<<dim3(512, 2), 256, 0, stream>>>(x, zc, dwf);
  fused_dct<<<256, 768, 0, stream>>>(zc, dwf, out);
}